// Round 1
// baseline (2129.478 us; speedup 1.0000x reference)
//
#include <hip/hip_runtime.h>
#include <math.h>

// Problem constants (from reference)
//   N_SRC = N_DST = 100000, E = 300000, FEAT = 256, RDIM = 128, REV_VOCAB = 500000
// Workspace layout (floats unless noted):
//   pa [E] f32 | ra [E] f32 | t [E*256] bf16 | h [N_DST*256] f32   => ~258.4 MB total

#define KT 16

__device__ __forceinline__ float bf2f(unsigned short v) {
    union { unsigned int u; float f; } x; x.u = ((unsigned int)v) << 16; return x.f;
}
__device__ __forceinline__ unsigned short f2bf(float f) {
    union { float f; unsigned int u; } x; x.f = f;
    unsigned int u = x.u;
    return (unsigned short)((u + 0x7FFFu + ((u >> 16) & 1u)) >> 16);
}
__device__ __forceinline__ float gelu_erf(float x) {
    return 0.5f * x * (1.0f + erff(x * 0.70710678118654752f));
}

// ---------------------------------------------------------------------------
// Per-edge pa/ra: one wave (64 lanes) per edge, 128-d dot with prob_w/score_w
// ---------------------------------------------------------------------------
__global__ __launch_bounds__(256) void pa_ra_kernel(
    const int* __restrict__ rid, const float* __restrict__ remb,
    const float* __restrict__ pw, const float* __restrict__ sw,
    float* __restrict__ pa, float* __restrict__ ra, int E)
{
    int gid  = blockIdx.x * blockDim.x + threadIdx.x;
    int wid  = gid >> 6;
    int lane = threadIdx.x & 63;
    if (wid >= E) return;
    int g = rid[wid];
    float2 r = *(const float2*)(remb + (size_t)g * 128 + lane * 2);
    float2 p = *(const float2*)(pw + lane * 2);
    float2 s = *(const float2*)(sw + lane * 2);
    float dp = r.x * p.x + r.y * p.y;
    float ds = r.x * s.x + r.y * s.y;
    #pragma unroll
    for (int off = 32; off > 0; off >>= 1) {
        dp += __shfl_down(dp, off);
        ds += __shfl_down(ds, off);
    }
    if (lane == 0) {
        pa[wid] = 1.0f / (1.0f + expf(-dp));
        ra[wid] = 1.0f / (1.0f + expf(-ds));
    }
}

// ---------------------------------------------------------------------------
// Tiled GEMM: C[M x 256] = A[M x K] @ W[256 x K]^T  (+ mode-specific epilogue)
//   MODE 1: A = review_emb[review_id[m]]  (K=128), epi = gelu -> t (bf16)
//   MODE 2: A = t (bf16, K=256),          epi = gelu -> t (bf16, in-place; safe:
//           full-N tile per block => each block reads only its own rows)
//   MODE 3: A = t (bf16, K=256),          epi = (feat[src]*pa + acc*ra)*cj ->
//           atomicAdd into h[dst]
//   MODE 4: A = h (f32, K=256),           epi = acc*ci + bias -> d_out
// Tile: BM=64, BN=256 (full), KT=16. Block (32,8)=256 thr, 8x8 micro-tile:
//   rows {ty*4+i, 32+ty*4+i}, cols {tx*4+j, 128+tx*4+j}
// ---------------------------------------------------------------------------
template <int MODE, int K>
__global__ __launch_bounds__(256) void gemm_kernel(
    const float* __restrict__ Af,          // MODE1: review_emb ; MODE4: h
    const unsigned short* Ab,              // MODE2/3: t (bf16) -- no restrict (MODE2 aliases outb)
    const int* __restrict__ rid,           // MODE1
    const float* __restrict__ W,           // [256][K] row-major
    unsigned short* outb,                  // MODE1/2: t
    float* __restrict__ outf,              // MODE3: h (atomic) ; MODE4: d_out
    int M,
    const float* __restrict__ pa, const float* __restrict__ ra,
    const float* __restrict__ cj, const int* __restrict__ esrc,
    const int* __restrict__ edst, const float* __restrict__ feat,
    const float* __restrict__ ci, const float* __restrict__ bias)
{
    __shared__ float As[KT][68];
    __shared__ float Bs[KT][260];
    __shared__ int   rid_s[64];
    __shared__ float pa_s[64], ra_s[64], cj_s[64], ci_s[64];
    __shared__ int   src_s[64], dst_s[64];

    const int tx = threadIdx.x;            // 0..31
    const int ty = threadIdx.y;            // 0..7
    const int t0 = ty * 32 + tx;           // 0..255
    const int row0 = blockIdx.x * 64;

    if (t0 < 64) {
        int gr = row0 + t0;
        bool v = gr < M;
        if constexpr (MODE == 1) rid_s[t0] = v ? rid[gr] : 0;
        if constexpr (MODE == 3) {
            if (v) {
                int s = esrc[gr];
                src_s[t0] = s; dst_s[t0] = edst[gr];
                pa_s[t0] = pa[gr]; ra_s[t0] = ra[gr]; cj_s[t0] = cj[s];
            } else {
                src_s[t0] = 0; dst_s[t0] = 0;
                pa_s[t0] = 0.f; ra_s[t0] = 0.f; cj_s[t0] = 0.f;
            }
        }
        if constexpr (MODE == 4) ci_s[t0] = v ? ci[gr] : 0.f;
    }

    float acc[2][2][4][4] = {};

    const int lrow = t0 >> 2;  // 0..63
    const int kq   = t0 & 3;   // 0..3

    for (int kb = 0; kb < K; kb += KT) {
        __syncthreads();
        // ---- stage A tile: 64 rows x KT (transposed into As[k][row]) ----
        {
            int gr = row0 + lrow;
            float av[4] = {0.f, 0.f, 0.f, 0.f};
            if (gr < M) {
                if constexpr (MODE == 1) {
                    const float* p = Af + (size_t)rid_s[lrow] * 128 + kb + kq * 4;
                    float4 v = *(const float4*)p;
                    av[0] = v.x; av[1] = v.y; av[2] = v.z; av[3] = v.w;
                } else if constexpr (MODE == 2 || MODE == 3) {
                    const unsigned short* p = Ab + (size_t)gr * 256 + kb + kq * 4;
                    ushort4 v = *(const ushort4*)p;
                    av[0] = bf2f(v.x); av[1] = bf2f(v.y);
                    av[2] = bf2f(v.z); av[3] = bf2f(v.w);
                } else {
                    const float* p = Af + (size_t)gr * 256 + kb + kq * 4;
                    float4 v = *(const float4*)p;
                    av[0] = v.x; av[1] = v.y; av[2] = v.z; av[3] = v.w;
                }
            }
            #pragma unroll
            for (int j = 0; j < 4; ++j) As[kq * 4 + j][lrow] = av[j];
        }
        // ---- stage B tile: 256 cols x KT (transposed into Bs[k][col]) ----
        #pragma unroll
        for (int p = 0; p < 4; ++p) {
            int col = lrow + p * 64;
            const float* wp = W + (size_t)col * K + kb + kq * 4;
            float4 v = *(const float4*)wp;
            Bs[kq * 4 + 0][col] = v.x; Bs[kq * 4 + 1][col] = v.y;
            Bs[kq * 4 + 2][col] = v.z; Bs[kq * 4 + 3][col] = v.w;
        }
        __syncthreads();
        // ---- compute ----
        #pragma unroll
        for (int k = 0; k < KT; ++k) {
            float a0[4], a1[4], b0[4], b1[4];
            *(float4*)a0 = *(const float4*)&As[k][ty * 4];
            *(float4*)a1 = *(const float4*)&As[k][32 + ty * 4];
            *(float4*)b0 = *(const float4*)&Bs[k][tx * 4];
            *(float4*)b1 = *(const float4*)&Bs[k][128 + tx * 4];
            #pragma unroll
            for (int i = 0; i < 4; ++i) {
                #pragma unroll
                for (int j = 0; j < 4; ++j) {
                    acc[0][0][i][j] += a0[i] * b0[j];
                    acc[0][1][i][j] += a0[i] * b1[j];
                    acc[1][0][i][j] += a1[i] * b0[j];
                    acc[1][1][i][j] += a1[i] * b1[j];
                }
            }
        }
    }

    // ---- epilogue ----
    #pragma unroll
    for (int p = 0; p < 2; ++p) {
        #pragma unroll
        for (int i = 0; i < 4; ++i) {
            int lr = p * 32 + ty * 4 + i;
            int gr = row0 + lr;
            if (gr >= M) continue;
            #pragma unroll
            for (int q = 0; q < 2; ++q) {
                int c = q * 128 + tx * 4;
                float v0 = acc[p][q][i][0], v1 = acc[p][q][i][1];
                float v2 = acc[p][q][i][2], v3 = acc[p][q][i][3];
                if constexpr (MODE == 1 || MODE == 2) {
                    ushort4 o;
                    o.x = f2bf(gelu_erf(v0)); o.y = f2bf(gelu_erf(v1));
                    o.z = f2bf(gelu_erf(v2)); o.w = f2bf(gelu_erf(v3));
                    *(ushort4*)(outb + (size_t)gr * 256 + c) = o;
                } else if constexpr (MODE == 3) {
                    float pav = pa_s[lr], rav = ra_s[lr], cjv = cj_s[lr];
                    int s = src_s[lr], d = dst_s[lr];
                    float4 fv = *(const float4*)(feat + (size_t)s * 256 + c);
                    float* hp = outf + (size_t)d * 256 + c;
                    atomicAdd(hp + 0, (fv.x * pav + v0 * rav) * cjv);
                    atomicAdd(hp + 1, (fv.y * pav + v1 * rav) * cjv);
                    atomicAdd(hp + 2, (fv.z * pav + v2 * rav) * cjv);
                    atomicAdd(hp + 3, (fv.w * pav + v3 * rav) * cjv);
                } else {
                    float civ = ci_s[lr];
                    float4 bv = *(const float4*)(bias + c);
                    float4 o;
                    o.x = v0 * civ + bv.x; o.y = v1 * civ + bv.y;
                    o.z = v2 * civ + bv.z; o.w = v3 * civ + bv.w;
                    *(float4*)(outf + (size_t)gr * 256 + c) = o;
                }
            }
        }
    }
}

extern "C" void kernel_launch(void* const* d_in, const int* in_sizes, int n_in,
                              void* d_out, int out_size, void* d_ws, size_t ws_size,
                              hipStream_t stream) {
    const float* feat = (const float*)d_in[0];
    const float* cj   = (const float*)d_in[1];
    const float* ci   = (const float*)d_in[2];
    const int*   esrc = (const int*)d_in[3];
    const int*   edst = (const int*)d_in[4];
    const int*   rid  = (const int*)d_in[5];
    const float* remb = (const float*)d_in[6];
    const float* pw   = (const float*)d_in[7];
    const float* sw   = (const float*)d_in[8];
    const float* rw1  = (const float*)d_in[9];
    const float* rw2  = (const float*)d_in[10];
    const float* rw3  = (const float*)d_in[11];
    const float* lw   = (const float*)d_in[12];
    const float* lb   = (const float*)d_in[13];
    float* out = (float*)d_out;

    const int E  = in_sizes[3];   // 300000
    const int ND = in_sizes[2];   // 100000

    // workspace carve-up
    char* ws = (char*)d_ws;
    float* pa = (float*)ws;                                   // E f32
    float* ra = pa + E;                                       // E f32
    unsigned short* t = (unsigned short*)(ra + E);            // E*256 bf16
    float* h = (float*)((char*)t + (size_t)E * 256 * 2);      // ND*256 f32

    hipMemsetAsync(h, 0, (size_t)ND * 256 * sizeof(float), stream);

    // pa/ra: one wave per edge
    {
        int blocks = (E + 3) / 4;
        pa_ra_kernel<<<blocks, 256, 0, stream>>>(rid, remb, pw, sw, pa, ra, E);
    }

    dim3 blk(32, 8, 1);
    int gE = (E + 63) / 64;
    int gD = (ND + 63) / 64;

    // t = gelu(gather(review_emb, review_id) @ rw1^T)
    gemm_kernel<1, 128><<<gE, blk, 0, stream>>>(
        remb, nullptr, rid, rw1, t, nullptr, E,
        nullptr, nullptr, nullptr, nullptr, nullptr, nullptr, nullptr, nullptr);
    // t = gelu(t @ rw2^T)   (in-place, row-local)
    gemm_kernel<2, 256><<<gE, blk, 0, stream>>>(
        nullptr, t, nullptr, rw2, t, nullptr, E,
        nullptr, nullptr, nullptr, nullptr, nullptr, nullptr, nullptr, nullptr);
    // rf = t @ rw3^T ; m = (feat[src]*pa + rf*ra)*cj[src] ; h[dst] += m
    gemm_kernel<3, 256><<<gE, blk, 0, stream>>>(
        nullptr, t, nullptr, rw3, nullptr, h, E,
        pa, ra, cj, esrc, edst, feat, nullptr, nullptr);
    // out = (h*ci) @ lin_w^T + lin_b
    gemm_kernel<4, 256><<<gD, blk, 0, stream>>>(
        h, nullptr, nullptr, lw, nullptr, out, ND,
        nullptr, nullptr, nullptr, nullptr, nullptr, nullptr, ci, lb);
}

// Round 2
// 1042.858 us; speedup vs baseline: 2.0420x; 2.0420x over previous
//
#include <hip/hip_runtime.h>
#include <math.h>
#include <stdint.h>

// Pipeline (E=300000 edges, ND=100000 dst, FEAT=256, RDIM=128):
//   prep:  convert rw1/rw2/rw3/lin_w to bf16 in ws
//   g1:    t = gelu(remb[rid] @ rw1^T)  (K=128) + fused pa/ra sigmoid dots
//   g2:    t = gelu(t @ rw2^T)          (in-place, row-local)
//   g3:    rf = t @ rw3^T ; m=(feat[src]*pa+rf*ra)*cj ; h[dst] += m  (pk bf16 atomics)
//   g4:    out = (h @ lin_w^T)*ci + b
// MFMA 16x16x32 bf16, 4 waves/block, BM=128 (32 rows/wave), full N=256 in regs.
// No LDS: A frags are per-lane contiguous 16B global loads (each byte read once);
// B frags come from the 128KB bf16 weight table (L1-resident per K-slice).

typedef short bf16x8 __attribute__((ext_vector_type(8)));
typedef float f32x4  __attribute__((ext_vector_type(4)));

__device__ __forceinline__ float bf2f(unsigned short v) {
    union { unsigned int u; float f; } x; x.u = ((unsigned int)v) << 16; return x.f;
}
__device__ __forceinline__ unsigned short f2bf(float f) {
    union { float f; unsigned int u; } x; x.f = f;
    unsigned int u = x.u;
    return (unsigned short)((u + 0x7FFFu + ((u >> 16) & 1u)) >> 16);
}
__device__ __forceinline__ float gelu_erf(float x) {
    return 0.5f * x * (1.0f + erff(x * 0.70710678118654752f));
}

__global__ __launch_bounds__(256) void prep_weights(
    const float* __restrict__ rw1, const float* __restrict__ rw2,
    const float* __restrict__ rw3, const float* __restrict__ lw,
    unsigned short* __restrict__ w1b, unsigned short* __restrict__ w2b,
    unsigned short* __restrict__ w3b, unsigned short* __restrict__ lwb)
{
    int i = blockIdx.x * blockDim.x + threadIdx.x;
    if (i < 256 * 128) w1b[i] = f2bf(rw1[i]);
    if (i < 256 * 256) {
        w2b[i] = f2bf(rw2[i]);
        w3b[i] = f2bf(rw3[i]);
        lwb[i] = f2bf(lw[i]);
    }
}

// ---------------------------------------------------------------------------
// C[M x 256] = A[M x K] @ W[256 x K]^T via mfma_f32_16x16x32_bf16
// Frag layouts (verified m89): A: row=lane&15, k=8*(lane>>4)+j
//                              B: col=lane&15, k=8*(lane>>4)+j
//                              D: row=4*(lane>>4)+reg, col=lane&15
// ---------------------------------------------------------------------------
template <int MODE, int K>
__global__ __launch_bounds__(256, 2) void mfma_gemm(
    const float* __restrict__ Af,          // MODE1: review_emb
    const unsigned short* Ab,              // MODE2/3: t ; MODE4: h   (no restrict: MODE2 aliases outb)
    const int* __restrict__ rid,           // MODE1
    const unsigned short* __restrict__ Wb, // [256][K] bf16
    unsigned short* outb,                  // MODE1/2: t
    float* __restrict__ outf,              // MODE4: d_out
    unsigned short* __restrict__ hb,       // MODE3: h (bf16, pk atomics)
    int M,
    const float* __restrict__ pw, const float* __restrict__ sw,
    float* __restrict__ pa, float* __restrict__ ra,
    const float* __restrict__ cj, const int* __restrict__ esrc,
    const int* __restrict__ edst, const float* __restrict__ feat,
    const float* __restrict__ ci, const float* __restrict__ bias)
{
    const int tid   = threadIdx.x;
    const int lane  = tid & 63;
    const int wid   = tid >> 6;
    const int l15   = lane & 15;
    const int kgrp  = lane >> 4;                 // 0..3
    const int wbase = blockIdx.x * 128 + wid * 32;

    const int r0 = wbase + l15;                  // A-frag 0 row
    const int r1 = wbase + 16 + l15;             // A-frag 1 row
    const int ar0 = (r0 < M) ? r0 : (M - 1);     // clamped for loads
    const int ar1 = (r1 < M) ? r1 : (M - 1);

    f32x4 acc[2][16];
    #pragma unroll
    for (int m = 0; m < 2; ++m)
        #pragma unroll
        for (int n = 0; n < 16; ++n)
            acc[m][n] = (f32x4)0.0f;

    int rid0 = 0, rid1 = 0;
    float pd0 = 0.f, pd1 = 0.f, rd0 = 0.f, rd1 = 0.f;
    if constexpr (MODE == 1) {
        rid0 = rid[ar0];
        rid1 = rid[ar1];
    }

    for (int k0 = 0; k0 < K; k0 += 32) {
        const int kk = k0 + kgrp * 8;
        bf16x8 a0, a1;
        if constexpr (MODE == 1) {
            const float* p0 = Af + (size_t)rid0 * 128 + kk;
            const float* p1 = Af + (size_t)rid1 * 128 + kk;
            float4 u0 = *(const float4*)p0, u1 = *(const float4*)(p0 + 4);
            float4 w0 = *(const float4*)p1, w1 = *(const float4*)(p1 + 4);
            float4 pv0 = *(const float4*)(pw + kk), pv1 = *(const float4*)(pw + kk + 4);
            float4 sv0 = *(const float4*)(sw + kk), sv1 = *(const float4*)(sw + kk + 4);
            float av0[8] = {u0.x, u0.y, u0.z, u0.w, u1.x, u1.y, u1.z, u1.w};
            float av1[8] = {w0.x, w0.y, w0.z, w0.w, w1.x, w1.y, w1.z, w1.w};
            float pv[8]  = {pv0.x, pv0.y, pv0.z, pv0.w, pv1.x, pv1.y, pv1.z, pv1.w};
            float sv[8]  = {sv0.x, sv0.y, sv0.z, sv0.w, sv1.x, sv1.y, sv1.z, sv1.w};
            #pragma unroll
            for (int j = 0; j < 8; ++j) {
                pd0 += av0[j] * pv[j];  rd0 += av0[j] * sv[j];
                pd1 += av1[j] * pv[j];  rd1 += av1[j] * sv[j];
                a0[j] = (short)f2bf(av0[j]);
                a1[j] = (short)f2bf(av1[j]);
            }
        } else {
            a0 = *(const bf16x8*)(Ab + (size_t)ar0 * 256 + kk);
            a1 = *(const bf16x8*)(Ab + (size_t)ar1 * 256 + kk);
        }
        const unsigned short* wbp = Wb + (size_t)l15 * K + kk;
        #pragma unroll
        for (int n = 0; n < 16; ++n) {
            bf16x8 b = *(const bf16x8*)(wbp + (size_t)(n * 16) * K);
            acc[0][n] = __builtin_amdgcn_mfma_f32_16x16x32_bf16(a0, b, acc[0][n], 0, 0, 0);
            acc[1][n] = __builtin_amdgcn_mfma_f32_16x16x32_bf16(a1, b, acc[1][n], 0, 0, 0);
        }
    }

    // fused pa/ra (MODE 1): reduce k-partition lanes, sigmoid, store
    if constexpr (MODE == 1) {
        pd0 += __shfl_xor(pd0, 16); pd0 += __shfl_xor(pd0, 32);
        rd0 += __shfl_xor(rd0, 16); rd0 += __shfl_xor(rd0, 32);
        pd1 += __shfl_xor(pd1, 16); pd1 += __shfl_xor(pd1, 32);
        rd1 += __shfl_xor(rd1, 16); rd1 += __shfl_xor(rd1, 32);
        if (lane < 16) {
            if (r0 < M) { pa[r0] = 1.f / (1.f + expf(-pd0)); ra[r0] = 1.f / (1.f + expf(-rd0)); }
        } else if (lane < 32) {
            int rr = wbase + 16 + l15;
            if (rr < M) { pa[rr] = 1.f / (1.f + expf(-pd1)); ra[rr] = 1.f / (1.f + expf(-rd1)); }
        }
    }

    // epilogue
    #pragma unroll
    for (int m = 0; m < 2; ++m) {
        const int rowb = wbase + m * 16 + kgrp * 4;
        if constexpr (MODE == 3) {
            #pragma unroll
            for (int r = 0; r < 4; ++r) {
                int e = rowb + r;
                bool v = e < M;                        // uniform across lane pairs
                int ec = v ? e : 0;
                int s = esrc[ec], d = edst[ec];
                float pav = pa[ec], rav = ra[ec], cjv = cj[s];
                #pragma unroll
                for (int n = 0; n < 16; ++n) {
                    int col = n * 16 + l15;
                    float fv  = feat[(size_t)s * 256 + col];
                    float val = (fv * pav + acc[m][n][r] * rav) * cjv;
                    float oth = __shfl_xor(val, 1);    // neighbor column
                    if (v && (lane & 1) == 0) {
                        unsigned pack = (unsigned)f2bf(val) | ((unsigned)f2bf(oth) << 16);
                        uint64_t addr = (uint64_t)(hb + (size_t)d * 256 + col);
                        asm volatile("global_atomic_pk_add_bf16 %0, %1, off"
                                     :: "v"(addr), "v"(pack) : "memory");
                    }
                }
            }
        } else if constexpr (MODE == 1 || MODE == 2) {
            #pragma unroll
            for (int r = 0; r < 4; ++r) {
                int gr = rowb + r;
                if (gr < M) {
                    #pragma unroll
                    for (int n = 0; n < 16; ++n)
                        outb[(size_t)gr * 256 + n * 16 + l15] = f2bf(gelu_erf(acc[m][n][r]));
                }
            }
        } else { // MODE 4
            #pragma unroll
            for (int r = 0; r < 4; ++r) {
                int gr = rowb + r;
                if (gr < M) {
                    float civ = ci[gr];
                    #pragma unroll
                    for (int n = 0; n < 16; ++n) {
                        int col = n * 16 + l15;
                        outf[(size_t)gr * 256 + col] = acc[m][n][r] * civ + bias[col];
                    }
                }
            }
        }
    }
}

extern "C" void kernel_launch(void* const* d_in, const int* in_sizes, int n_in,
                              void* d_out, int out_size, void* d_ws, size_t ws_size,
                              hipStream_t stream) {
    const float* feat = (const float*)d_in[0];
    const float* cj   = (const float*)d_in[1];
    const float* ci   = (const float*)d_in[2];
    const int*   esrc = (const int*)d_in[3];
    const int*   edst = (const int*)d_in[4];
    const int*   rid  = (const int*)d_in[5];
    const float* remb = (const float*)d_in[6];
    const float* pw   = (const float*)d_in[7];
    const float* sw   = (const float*)d_in[8];
    const float* rw1  = (const float*)d_in[9];
    const float* rw2  = (const float*)d_in[10];
    const float* rw3  = (const float*)d_in[11];
    const float* lw   = (const float*)d_in[12];
    const float* lb   = (const float*)d_in[13];
    float* out = (float*)d_out;

    const int E  = in_sizes[3];   // 300000
    const int ND = in_sizes[2];   // 100000

    // workspace carve-up (16B-aligned sections)
    char* ws = (char*)d_ws;
    float* pa = (float*)ws;                                        // E f32
    float* ra = pa + E;                                            // E f32
    unsigned short* t  = (unsigned short*)(ra + E);                // E*256 bf16
    unsigned short* h  = t + (size_t)E * 256;                      // ND*256 bf16
    unsigned short* w1b = h + (size_t)ND * 256;                    // 256*128
    unsigned short* w2b = w1b + 256 * 128;                         // 256*256
    unsigned short* w3b = w2b + 256 * 256;
    unsigned short* lwb = w3b + 256 * 256;

    hipMemsetAsync(h, 0, (size_t)ND * 256 * sizeof(unsigned short), stream);
    prep_weights<<<256, 256, 0, stream>>>(rw1, rw2, rw3, lw, w1b, w2b, w3b, lwb);

    int gE = (E + 127) / 128;
    int gD = (ND + 127) / 128;

    // g1: t = gelu(remb[rid] @ rw1^T), fused pa/ra
    mfma_gemm<1, 128><<<gE, 256, 0, stream>>>(
        remb, nullptr, rid, w1b, t, nullptr, nullptr, E,
        pw, sw, pa, ra, nullptr, nullptr, nullptr, nullptr, nullptr, nullptr);
    // g2: t = gelu(t @ rw2^T)  (in-place, row-local)
    mfma_gemm<2, 256><<<gE, 256, 0, stream>>>(
        nullptr, t, nullptr, w2b, t, nullptr, nullptr, E,
        nullptr, nullptr, nullptr, nullptr, nullptr, nullptr, nullptr, nullptr, nullptr, nullptr);
    // g3: rf = t @ rw3^T ; h[dst] += (feat[src]*pa + rf*ra)*cj  (pk bf16 atomics)
    mfma_gemm<3, 256><<<gE, 256, 0, stream>>>(
        nullptr, t, nullptr, w3b, nullptr, nullptr, h, E,
        nullptr, nullptr, pa, ra, cj, esrc, edst, feat, nullptr, nullptr);
    // g4: out = (h @ lin_w^T)*ci + b
    mfma_gemm<4, 256><<<gD, 256, 0, stream>>>(
        nullptr, h, nullptr, lwb, nullptr, out, nullptr, ND,
        nullptr, nullptr, nullptr, nullptr, nullptr, nullptr, nullptr, nullptr, ci, lb);
}

// Round 3
// 775.212 us; speedup vs baseline: 2.7470x; 1.3453x over previous
//
#include <hip/hip_runtime.h>
#include <math.h>
#include <stdint.h>

// Pipeline (E=300000 edges, ND=100000 dst, FEAT=256, RDIM=128):
//   prep:   weights -> bf16; cnt=0
//   CSR:    hist (within[e]), block scan, bsum scan, add offsets, counting sort -> eidx
//   g1:     t = gelu(remb[rid] @ rw1^T) (K=128) + fused ga/gb = sigmoid(dots)*cj[src]
//   g2:     t = gelu(t @ rw2^T)                  (in-place, row-local)
//   g3:     m = feat[src]*ga + (t @ rw3^T)*gb    (in-place over t, row-local)
//   segsum: h[d] = sum over CSR range of m rows  (f32 accum, bf16 out)
//   g4:     out = (h @ lin_w^T)*ci + b
// GEMM: mfma_f32_32x32x16_bf16, 4 waves/block, wave = 64 rows x 128 cols
// (acc 8 x f32x16 = 128 VGPR), block = 128 rows x 256 cols. No LDS; B slices
// are L1-resident (128KB bf16 weight tables).

typedef short bf16x8 __attribute__((ext_vector_type(8)));
typedef float f32x16 __attribute__((ext_vector_type(16)));

__device__ __forceinline__ float bf2f(unsigned short v) {
    union { unsigned int u; float f; } x; x.u = ((unsigned int)v) << 16; return x.f;
}
__device__ __forceinline__ unsigned short f2bf(float f) {
    union { float f; unsigned int u; } x; x.f = f;
    unsigned int u = x.u;
    return (unsigned short)((u + 0x7FFFu + ((u >> 16) & 1u)) >> 16);
}
__device__ __forceinline__ float gelu_erf(float x) {
    return 0.5f * x * (1.0f + erff(x * 0.70710678118654752f));
}
__device__ __forceinline__ float sigmoidf(float x) {
    return 1.0f / (1.0f + expf(-x));
}

__global__ __launch_bounds__(256) void prep_weights(
    const float* __restrict__ rw1, const float* __restrict__ rw2,
    const float* __restrict__ rw3, const float* __restrict__ lw,
    unsigned short* __restrict__ w1b, unsigned short* __restrict__ w2b,
    unsigned short* __restrict__ w3b, unsigned short* __restrict__ lwb)
{
    int i = blockIdx.x * blockDim.x + threadIdx.x;
    if (i < 256 * 128) w1b[i] = f2bf(rw1[i]);
    if (i < 256 * 256) {
        w2b[i] = f2bf(rw2[i]);
        w3b[i] = f2bf(rw3[i]);
        lwb[i] = f2bf(lw[i]);
    }
}

// ---------------- CSR build ----------------
__global__ __launch_bounds__(256) void hist_kernel(
    const int* __restrict__ edst, int* __restrict__ cnt,
    int* __restrict__ within, int E)
{
    int e = blockIdx.x * blockDim.x + threadIdx.x;
    if (e < E) within[e] = atomicAdd(&cnt[edst[e]], 1);
}

__global__ __launch_bounds__(1024) void scan_block(
    const int* __restrict__ cnt, int* __restrict__ start,
    int* __restrict__ bsum, int n)
{
    __shared__ int s[1024];
    int gid = blockIdx.x * 1024 + threadIdx.x;
    int v = (gid < n) ? cnt[gid] : 0;
    s[threadIdx.x] = v;
    __syncthreads();
    #pragma unroll
    for (int off = 1; off < 1024; off <<= 1) {
        int t = (threadIdx.x >= off) ? s[threadIdx.x - off] : 0;
        __syncthreads();
        if (threadIdx.x >= off) s[threadIdx.x] += t;
        __syncthreads();
    }
    if (gid < n) start[gid] = s[threadIdx.x] - v;   // exclusive
    if (threadIdx.x == 1023) bsum[blockIdx.x] = s[1023];
}

__global__ void scan_bsum(int* __restrict__ bsum, int nb) {
    if (threadIdx.x == 0 && blockIdx.x == 0) {
        int acc = 0;
        for (int i = 0; i < nb; ++i) { int v = bsum[i]; bsum[i] = acc; acc += v; }
    }
}

__global__ __launch_bounds__(1024) void add_offsets(
    int* __restrict__ start, const int* __restrict__ bsum, int n, int E)
{
    int gid = blockIdx.x * 1024 + threadIdx.x;
    if (gid < n) start[gid] += bsum[gid >> 10];
    if (gid == 0) start[n] = E;
}

__global__ __launch_bounds__(256) void build_eidx(
    const int* __restrict__ edst, const int* __restrict__ within,
    const int* __restrict__ start, int* __restrict__ eidx, int E)
{
    int e = blockIdx.x * blockDim.x + threadIdx.x;
    if (e < E) eidx[start[edst[e]] + within[e]] = e;
}

// ---------------- segment sum: one wave per dst ----------------
__global__ __launch_bounds__(256) void segsum_kernel(
    const int* __restrict__ start, const int* __restrict__ eidx,
    const unsigned short* __restrict__ m, unsigned short* __restrict__ h, int ND)
{
    int d = blockIdx.x * 4 + (threadIdx.x >> 6);
    if (d >= ND) return;
    int lane = threadIdx.x & 63;
    int s0 = start[d], s1 = start[d + 1];
    float a0 = 0.f, a1 = 0.f, a2 = 0.f, a3 = 0.f;
    for (int i = s0; i < s1; ++i) {
        int e = eidx[i];
        ushort4 v = *(const ushort4*)(m + (size_t)e * 256 + lane * 4);
        a0 += bf2f(v.x); a1 += bf2f(v.y); a2 += bf2f(v.z); a3 += bf2f(v.w);
    }
    ushort4 o; o.x = f2bf(a0); o.y = f2bf(a1); o.z = f2bf(a2); o.w = f2bf(a3);
    *(ushort4*)(h + (size_t)d * 256 + lane * 4) = o;
}

// ---------------------------------------------------------------------------
// C[M x 256] = A[M x K] @ W[256 x K]^T via mfma_f32_32x32x16_bf16
// A frag: row = lane&31 (+32 for 2nd m-frag), k = 8*(lane>>5)+j
// B frag: col = lane&31, k = 8*(lane>>5)+j
// D frag: col = lane&31, row = (reg&3)+8*(reg>>2)+4*(lane>>5)
// Wave: 64 rows x 128 cols; block: 128 rows x 256 cols.
// ---------------------------------------------------------------------------
template <int MODE, int K>
__global__ __launch_bounds__(256, 2) void mfma_gemm(
    const float* __restrict__ Af,          // MODE1: review_emb
    const unsigned short* Ab,              // MODE2/3: t ; MODE4: h (no restrict: in-place alias)
    const int* __restrict__ rid,           // MODE1
    const unsigned short* __restrict__ Wb, // [256][K] bf16
    unsigned short* outb,                  // MODE1/2: t ; MODE3: m (= t)
    float* __restrict__ outf,              // MODE4: d_out
    int M,
    const float* __restrict__ pw, const float* __restrict__ sw,
    float* __restrict__ ga, float* __restrict__ gb,
    const float* __restrict__ cj, const int* __restrict__ esrc,
    const float* __restrict__ feat,
    const float* __restrict__ ci, const float* __restrict__ bias)
{
    const int tid  = threadIdx.x;
    const int lane = tid & 63;
    const int wid  = tid >> 6;
    const int l31  = lane & 31;
    const int kg   = lane >> 5;                       // 0..1
    const int colh = (wid & 1) * 128;                 // column half
    const int wbase = blockIdx.x * 128 + (wid >> 1) * 64;

    const int r0 = wbase + l31;
    const int r1 = wbase + 32 + l31;
    const int ar0 = (r0 < M) ? r0 : (M - 1);
    const int ar1 = (r1 < M) ? r1 : (M - 1);

    f32x16 acc[2][4];
    #pragma unroll
    for (int mi = 0; mi < 2; ++mi)
        #pragma unroll
        for (int n = 0; n < 4; ++n)
            acc[mi][n] = (f32x16)0.0f;

    int rid0 = 0, rid1 = 0;
    float pd0 = 0.f, pd1 = 0.f, rd0 = 0.f, rd1 = 0.f;
    if constexpr (MODE == 1) { rid0 = rid[ar0]; rid1 = rid[ar1]; }

    for (int k0 = 0; k0 < K; k0 += 16) {
        const int kk = k0 + kg * 8;
        bf16x8 a0, a1;
        if constexpr (MODE == 1) {
            const float* p0 = Af + (size_t)rid0 * 128 + kk;
            const float* p1 = Af + (size_t)rid1 * 128 + kk;
            float4 u0 = *(const float4*)p0, u1 = *(const float4*)(p0 + 4);
            float4 w0 = *(const float4*)p1, w1 = *(const float4*)(p1 + 4);
            float4 pv0 = *(const float4*)(pw + kk), pv1 = *(const float4*)(pw + kk + 4);
            float4 sv0 = *(const float4*)(sw + kk), sv1 = *(const float4*)(sw + kk + 4);
            float av0[8] = {u0.x, u0.y, u0.z, u0.w, u1.x, u1.y, u1.z, u1.w};
            float av1[8] = {w0.x, w0.y, w0.z, w0.w, w1.x, w1.y, w1.z, w1.w};
            float pv[8]  = {pv0.x, pv0.y, pv0.z, pv0.w, pv1.x, pv1.y, pv1.z, pv1.w};
            float sv[8]  = {sv0.x, sv0.y, sv0.z, sv0.w, sv1.x, sv1.y, sv1.z, sv1.w};
            #pragma unroll
            for (int j = 0; j < 8; ++j) {
                pd0 += av0[j] * pv[j];  rd0 += av0[j] * sv[j];
                pd1 += av1[j] * pv[j];  rd1 += av1[j] * sv[j];
                a0[j] = (short)f2bf(av0[j]);
                a1[j] = (short)f2bf(av1[j]);
            }
        } else {
            a0 = *(const bf16x8*)(Ab + (size_t)ar0 * 256 + kk);
            a1 = *(const bf16x8*)(Ab + (size_t)ar1 * 256 + kk);
        }
        const unsigned short* wbp = Wb + (size_t)(colh + l31) * K + kk;
        #pragma unroll
        for (int n = 0; n < 4; ++n) {
            bf16x8 b = *(const bf16x8*)(wbp + (size_t)(n * 32) * K);
            acc[0][n] = __builtin_amdgcn_mfma_f32_32x32x16_bf16(a0, b, acc[0][n], 0, 0, 0);
            acc[1][n] = __builtin_amdgcn_mfma_f32_32x32x16_bf16(a1, b, acc[1][n], 0, 0, 0);
        }
    }

    // fused ga/gb (MODE 1): reduce across the two k-groups, sigmoid * cj[src]
    if constexpr (MODE == 1) {
        pd0 += __shfl_xor(pd0, 32); rd0 += __shfl_xor(rd0, 32);
        pd1 += __shfl_xor(pd1, 32); rd1 += __shfl_xor(rd1, 32);
        if (kg == 0 && colh == 0) {
            if (r0 < M) {
                float c = cj[esrc[r0]];
                ga[r0] = sigmoidf(pd0) * c; gb[r0] = sigmoidf(rd0) * c;
            }
            if (r1 < M) {
                float c = cj[esrc[r1]];
                ga[r1] = sigmoidf(pd1) * c; gb[r1] = sigmoidf(rd1) * c;
            }
        }
    }

    // in-place modes: all reads of this block's A rows must finish first
    if constexpr (MODE == 2 || MODE == 3) __syncthreads();

    // epilogue
    #pragma unroll
    for (int mi = 0; mi < 2; ++mi) {
        #pragma unroll
        for (int r = 0; r < 16; ++r) {
            const int gr = wbase + mi * 32 + (r & 3) + 8 * (r >> 2) + 4 * kg;
            if (gr >= M) continue;
            if constexpr (MODE == 1 || MODE == 2) {
                #pragma unroll
                for (int n = 0; n < 4; ++n)
                    outb[(size_t)gr * 256 + colh + n * 32 + l31] =
                        f2bf(gelu_erf(acc[mi][n][r]));
            } else if constexpr (MODE == 3) {
                int s = esrc[gr];
                float gav = ga[gr], gbv = gb[gr];
                const float* fp = feat + (size_t)s * 256 + colh;
                #pragma unroll
                for (int n = 0; n < 4; ++n) {
                    float val = fp[n * 32 + l31] * gav + acc[mi][n][r] * gbv;
                    outb[(size_t)gr * 256 + colh + n * 32 + l31] = f2bf(val);
                }
            } else {
                float civ = ci[gr];
                #pragma unroll
                for (int n = 0; n < 4; ++n) {
                    int col = colh + n * 32 + l31;
                    outf[(size_t)gr * 256 + col] = acc[mi][n][r] * civ + bias[col];
                }
            }
        }
    }
}

extern "C" void kernel_launch(void* const* d_in, const int* in_sizes, int n_in,
                              void* d_out, int out_size, void* d_ws, size_t ws_size,
                              hipStream_t stream) {
    const float* feat = (const float*)d_in[0];
    const float* cj   = (const float*)d_in[1];
    const float* ci   = (const float*)d_in[2];
    const int*   esrc = (const int*)d_in[3];
    const int*   edst = (const int*)d_in[4];
    const int*   rid  = (const int*)d_in[5];
    const float* remb = (const float*)d_in[6];
    const float* pw   = (const float*)d_in[7];
    const float* sw   = (const float*)d_in[8];
    const float* rw1  = (const float*)d_in[9];
    const float* rw2  = (const float*)d_in[10];
    const float* rw3  = (const float*)d_in[11];
    const float* lw   = (const float*)d_in[12];
    const float* lb   = (const float*)d_in[13];
    float* out = (float*)d_out;

    const int E  = in_sizes[3];   // 300000
    const int ND = in_sizes[2];   // 100000

    // workspace carve-up
    char* ws = (char*)d_ws;
    float* ga = (float*)ws;                                        // E f32
    float* gb = ga + E;                                            // E f32
    unsigned short* t   = (unsigned short*)(gb + E);               // E*256 bf16 (aliased as m)
    unsigned short* h   = t + (size_t)E * 256;                     // ND*256 bf16
    unsigned short* w1b = h + (size_t)ND * 256;                    // 256*128
    unsigned short* w2b = w1b + 256 * 128;                         // 256*256
    unsigned short* w3b = w2b + 256 * 256;
    unsigned short* lwb = w3b + 256 * 256;
    int* cnt    = (int*)(lwb + 256 * 256);                         // ND
    int* start  = cnt + ND;                                        // ND+1
    int* bsum   = start + ND + 1;                                  // 128
    int* within = bsum + 128;                                      // E
    int* eidx   = within + E;                                      // E

    const int NB = (ND + 1023) / 1024;  // scan blocks (98)

    hipMemsetAsync(cnt, 0, (size_t)ND * sizeof(int), stream);
    prep_weights<<<256, 256, 0, stream>>>(rw1, rw2, rw3, lw, w1b, w2b, w3b, lwb);

    // CSR build
    hist_kernel<<<(E + 255) / 256, 256, 0, stream>>>(edst, cnt, within, E);
    scan_block<<<NB, 1024, 0, stream>>>(cnt, start, bsum, ND);
    scan_bsum<<<1, 64, 0, stream>>>(bsum, NB);
    add_offsets<<<NB, 1024, 0, stream>>>(start, bsum, ND, E);
    build_eidx<<<(E + 255) / 256, 256, 0, stream>>>(edst, within, start, eidx, E);

    int gE = (E + 127) / 128;
    int gD = (ND + 127) / 128;

    // g1: t = gelu(remb[rid] @ rw1^T), fused ga/gb
    mfma_gemm<1, 128><<<gE, 256, 0, stream>>>(
        remb, nullptr, rid, w1b, t, nullptr, E,
        pw, sw, ga, gb, cj, esrc, nullptr, nullptr, nullptr);
    // g2: t = gelu(t @ rw2^T)   (in-place)
    mfma_gemm<2, 256><<<gE, 256, 0, stream>>>(
        nullptr, t, nullptr, w2b, t, nullptr, E,
        nullptr, nullptr, nullptr, nullptr, nullptr, nullptr, nullptr, nullptr, nullptr);
    // g3: m = feat[src]*ga + (t @ rw3^T)*gb   (in-place over t)
    mfma_gemm<3, 256><<<gE, 256, 0, stream>>>(
        nullptr, t, nullptr, w3b, t, nullptr, E,
        nullptr, nullptr, ga, gb, nullptr, esrc, feat, nullptr, nullptr);
    // segsum: h[d] = sum of m rows for d's edges
    segsum_kernel<<<(ND + 3) / 4, 256, 0, stream>>>(start, eidx, t, h, ND);
    // g4: out = (h @ lin_w^T)*ci + b
    mfma_gemm<4, 256><<<gD, 256, 0, stream>>>(
        nullptr, h, nullptr, lwb, nullptr, out, ND,
        nullptr, nullptr, nullptr, nullptr, nullptr, nullptr, nullptr, ci, lb);
}